// Round 6
// baseline (15865.134 us; speedup 1.0000x reference)
//
#include <hip/hip_runtime.h>
#include <hip/hip_fp16.h>

// LSTM: B=256, T=1024, D=128, H=256.
// w16_kernel: W x-part -> f16 table; zeroes the 32 exchange flags (runs first).
// gx_kernel : Gx[b,t,g] = x@Wx^T + bias, f16, tile layout [tl][bg][t64][lane][4].
// rec_kernel: 32 WGs (16 bg x 2 h-halves) x 512 thr, 2 waves/SIMD. All Wh frags
//             in registers (128/wave). Pair WGs exchange h-halves per step via
//             AGENT-scope atomic ull stores/loads (L1-bypassing, XCD-safe) with a
//             release/acquire flag handshake. Own-half MFMA overlaps the wait.
// head_kernel: out[b] = sigmoid([hid, cov] @ W2^T + b2).

typedef _Float16 half8 __attribute__((ext_vector_type(8)));
typedef float f32x4 __attribute__((ext_vector_type(4)));

#define MFMA16(a, b, c) __builtin_amdgcn_mfma_f32_16x16x32_f16((a), (b), (c), 0, 0, 0)

__device__ __forceinline__ float2 h2f2(unsigned int u) {
  __half2 h;
  __builtin_memcpy(&h, &u, 4);
  return __half22float2(h);
}

// ---------------------------------------------------------------------------
// W x-part -> f16 (rows g = q*256 + r, cols 0..127) + flag reset.
// ---------------------------------------------------------------------------
__global__ void w16_kernel(const float* __restrict__ Wi, const float* __restrict__ Wf,
                           const float* __restrict__ Wo, const float* __restrict__ Wc,
                           __half* __restrict__ w16x, unsigned* __restrict__ flags)
{
  int g = blockIdx.x, c = threadIdx.x;  // 1024 blocks x 128 threads
  if (g == 0 && c < 32) flags[c] = 0;   // reset exchange flags once per launch
  int q = g >> 8;
  const float* Wq = (q == 0) ? Wi : (q == 1) ? Wf : (q == 2) ? Wo : Wc;
  w16x[g * 128 + c] = __float2half_rn(Wq[(size_t)(g & 255) * 384 + c]);
}

// ---------------------------------------------------------------------------
// Phase 1: x-part GEMM, no LDS. grid=(TC/8, 16, 2), 256 thr (4 waves).
// Output: t64 = gbase>>4 = q*16 + coltile; idx = ((tl*16+bg)*64 + t64)*256 + l*4.
// ---------------------------------------------------------------------------
__global__ __launch_bounds__(256) void gx_kernel(
    const __half* __restrict__ w16x,
    const float* __restrict__ bi, const float* __restrict__ bf,
    const float* __restrict__ bo, const float* __restrict__ bc,
    const float* __restrict__ x, __half* __restrict__ gx, int t0)
{
  const int tid = threadIdx.x;
  const int l = tid & 63, wv = tid >> 6;
  const int kq = l >> 4, col = l & 15;
  const int tch = blockIdx.x, bg = blockIdx.y, gh = blockIdx.z;
  const size_t brow = (size_t)(bg * 16 + col);

#pragma unroll
  for (int mh = 0; mh < 2; ++mh) {
    half8 afr[4][4];
#pragma unroll
    for (int mm = 0; mm < 4; ++mm) {
      int tt = t0 + tch * 8 + mh * 4 + mm;
      const float* xp = x + (brow * 1024 + tt) * 128 + kq * 8;
#pragma unroll
      for (int k = 0; k < 4; ++k) {
        float4 a = *(const float4*)(xp + k * 32);
        float4 b = *(const float4*)(xp + k * 32 + 4);
        afr[mm][k] = {(_Float16)a.x, (_Float16)a.y, (_Float16)a.z, (_Float16)a.w,
                      (_Float16)b.x, (_Float16)b.y, (_Float16)b.z, (_Float16)b.w};
      }
    }
#pragma unroll
    for (int n = 0; n < 8; ++n) {
      int gbase = gh * 512 + wv * 128 + n * 16;
      int gcol = gbase + col;
      int q = gcol >> 8;
      const float* Bq = (q == 0) ? bi : (q == 1) ? bf : (q == 2) ? bo : bc;
      float bv = Bq[gcol & 255];
      half8 wf[4];
#pragma unroll
      for (int k = 0; k < 4; ++k)
        wf[k] = *(const half8*)(w16x + (size_t)(gbase + col) * 128 + k * 32 + kq * 8);
#pragma unroll
      for (int mm = 0; mm < 4; ++mm) {
        f32x4 acc = {bv, bv, bv, bv};
#pragma unroll
        for (int k = 0; k < 4; ++k) acc = MFMA16(afr[mm][k], wf[k], acc);
        int tl = tch * 8 + mh * 4 + mm;
        size_t idx = (((size_t)tl * 16 + bg) * 64 + (gbase >> 4)) * 256 + l * 4;
        unsigned int lo = (unsigned int)__half_as_ushort(__float2half_rn(acc[0])) |
                          ((unsigned int)__half_as_ushort(__float2half_rn(acc[1])) << 16);
        unsigned int hi = (unsigned int)__half_as_ushort(__float2half_rn(acc[2])) |
                          ((unsigned int)__half_as_ushort(__float2half_rn(acc[3])) << 16);
        uint2 v = {lo, hi};
        *(uint2*)(gx + idx) = v;
      }
    }
  }
}

// ---------------------------------------------------------------------------
// Phase 2: recurrence. 32 WGs (bg = bid&15, hh = bid>>4, partner = bid^16).
// hbuf: 2 bufs x 16 bg x [256 cols][16 rows] f16 (ull index = col*4 + rowquad).
// ---------------------------------------------------------------------------
__global__ __launch_bounds__(512) __attribute__((amdgpu_waves_per_eu(2, 2)))
void rec_kernel(
    const float* __restrict__ Wi, const float* __restrict__ Wf,
    const float* __restrict__ Wo, const float* __restrict__ Wc,
    const __half* __restrict__ gx, float* __restrict__ dout,
    float* __restrict__ c_plain, float* __restrict__ c_state,
    __half* __restrict__ h_state, __half* __restrict__ hbuf,
    unsigned* __restrict__ flags, int t0, int tc)
{
  __shared__ char hlds[2][8192];  // [16 rows][256 cols] f16, XOR-swizzled rows
  const int tid = threadIdx.x;
  const int l = tid & 63, w = tid >> 6;
  const int kq = l >> 4, col = l & 15;
  const int bid = blockIdx.x;
  const int bg = bid & 15, hh = bid >> 4;
  const int tile = hh * 8 + w;     // global col-tile in [0,16)
  const int j = tile * 16 + col;   // global h column

  // ---- Wh fragments, all in registers: wfr[gate][k-frag] ----
  half8 wfr[4][8];
#pragma unroll
  for (int q = 0; q < 4; ++q) {
    const float* Wq = (q == 0) ? Wi : (q == 1) ? Wf : (q == 2) ? Wo : Wc;
    const float* src = Wq + (size_t)j * 384 + 128 + kq * 8;
#pragma unroll
    for (int kk = 0; kk < 8; ++kk) {
      float4 a = *(const float4*)(src + kk * 32);
      float4 b = *(const float4*)(src + kk * 32 + 4);
      wfr[q][kk] = {(_Float16)a.x, (_Float16)a.y, (_Float16)a.z, (_Float16)a.w,
                    (_Float16)b.x, (_Float16)b.y, (_Float16)b.z, (_Float16)b.w};
    }
  }

  // ---- state init / restore into hlds[t0&1] ----
  float cst[4];
  if (t0 == 0) {
#pragma unroll
    for (int rg = 0; rg < 4; ++rg) cst[rg] = 0.f;
    uint4 z = {0, 0, 0, 0};
    *(uint4*)(hlds[0] + tid * 16) = z;
  } else {
#pragma unroll
    for (int rg = 0; rg < 4; ++rg) cst[rg] = c_state[(size_t)bid * 2048 + tid * 4 + rg];
    int row = tid >> 5, c16 = tid & 31;
    uint4 v = *(const uint4*)(h_state + (size_t)bg * 4096 + row * 256 + c16 * 8);
    *(uint4*)(hlds[t0 & 1] + row * 512 + ((c16 * 16) ^ ((row & 7) << 4))) = v;
  }
  __syncthreads();

  // gx: this wave's 4 gate-tiles; gate q at +q*8192 B, local step stride 524288 B.
  const char* gxp = (const char*)gx + ((size_t)bg * 64 + tile) * 512 + l * 8;
  uint2 gxv[4];
#pragma unroll
  for (int q = 0; q < 4; ++q) gxv[q] = *(const uint2*)(gxp + q * 8192);

  const int rswz = (l & 7) << 4;
  const int rbase = (l & 15) * 512;
  const int sc = (hh ^ 1) * 128 + (tid >> 2);  // staging col
  const int sr4 = tid & 3;                     // staging row-quad

  for (int tt = 0; tt < tc; ++tt) {
    const int s = t0 + tt;
    char* rb = hlds[s & 1];
    char* wb = hlds[(s & 1) ^ 1];

    // ---- (i)+(ii) own-half MFMA (overlaps partner's publish latency) ----
    f32x4 acc[4] = {{0.f, 0.f, 0.f, 0.f}, {0.f, 0.f, 0.f, 0.f},
                    {0.f, 0.f, 0.f, 0.f}, {0.f, 0.f, 0.f, 0.f}};
    {
      half8 afr[4];
#pragma unroll
      for (int k2 = 0; k2 < 4; ++k2) {
        int kk = hh * 4 + k2;
        afr[k2] = *(const half8*)(rb + rbase + ((kk * 64 + kq * 16) ^ rswz));
      }
#pragma unroll
      for (int k2 = 0; k2 < 4; ++k2) {
        acc[0] = MFMA16(afr[k2], wfr[0][hh * 4 + k2], acc[0]);
        acc[1] = MFMA16(afr[k2], wfr[1][hh * 4 + k2], acc[1]);
        acc[2] = MFMA16(afr[k2], wfr[2][hh * 4 + k2], acc[2]);
        acc[3] = MFMA16(afr[k2], wfr[3][hh * 4 + k2], acc[3]);
      }
    }

    // ---- prefetch next step's gx ----
    const int tn = (tt + 1 < tc) ? tt + 1 : tt;
    uint2 gnv[4];
#pragma unroll
    for (int q = 0; q < 4; ++q)
      gnv[q] = *(const uint2*)(gxp + (size_t)tn * 524288 + q * 8192);

    // ---- (iii) spin + stage partner half of h_s (skip at chunk start) ----
    if (tt > 0) {
      const unsigned tgt = (unsigned)s;
      while (__hip_atomic_load(&flags[bid ^ 16], __ATOMIC_RELAXED,
                               __HIP_MEMORY_SCOPE_AGENT) < tgt) {}
      __builtin_amdgcn_fence(__ATOMIC_ACQUIRE, "agent");
      const unsigned long long* hbR =
          (const unsigned long long*)hbuf + (((size_t)(s & 1)) * 16 + bg) * 1024;
      unsigned long long v = __hip_atomic_load(hbR + (size_t)sc * 4 + sr4,
                                               __ATOMIC_RELAXED, __HIP_MEMORY_SCOPE_AGENT);
#pragma unroll
      for (int e = 0; e < 4; ++e) {
        int r = sr4 * 4 + e;
        *(unsigned short*)(rb + r * 512 + ((sc * 2) ^ ((r & 7) << 4))) =
            (unsigned short)(v >> (16 * e));
      }
      __syncthreads();
    }

    // ---- (v) partner-half MFMA ----
    {
      half8 afr[4];
#pragma unroll
      for (int k2 = 0; k2 < 4; ++k2) {
        int kk = (hh ^ 1) * 4 + k2;
        afr[k2] = *(const half8*)(rb + rbase + ((kk * 64 + kq * 16) ^ rswz));
      }
#pragma unroll
      for (int k2 = 0; k2 < 4; ++k2) {
        acc[0] = MFMA16(afr[k2], wfr[0][(hh ^ 1) * 4 + k2], acc[0]);
        acc[1] = MFMA16(afr[k2], wfr[1][(hh ^ 1) * 4 + k2], acc[1]);
        acc[2] = MFMA16(afr[k2], wfr[2][(hh ^ 1) * 4 + k2], acc[2]);
        acc[3] = MFMA16(afr[k2], wfr[3][(hh ^ 1) * 4 + k2], acc[3]);
      }
    }

    // ---- (vi) gx add + activations ----
    const bool lastT = (s == 1023);
    unsigned short us[4];
#pragma unroll
    for (int rg = 0; rg < 4; ++rg) {
      float2 p01;
      p01 = (rg < 2) ? float2{0.f, 0.f} : float2{0.f, 0.f};  // (placeholder fold)
      float a_i = acc[0][rg], a_f = acc[1][rg], a_o = acc[2][rg], a_c = acc[3][rg];
      {
        float2 g0 = h2f2(gxv[0].x), g1 = h2f2(gxv[0].y);
        a_i += (rg < 2) ? ((rg == 0) ? g0.x : g0.y) : ((rg == 2) ? g1.x : g1.y);
      }
      {
        float2 g0 = h2f2(gxv[1].x), g1 = h2f2(gxv[1].y);
        a_f += (rg < 2) ? ((rg == 0) ? g0.x : g0.y) : ((rg == 2) ? g1.x : g1.y);
      }
      {
        float2 g0 = h2f2(gxv[2].x), g1 = h2f2(gxv[2].y);
        a_o += (rg < 2) ? ((rg == 0) ? g0.x : g0.y) : ((rg == 2) ? g1.x : g1.y);
      }
      {
        float2 g0 = h2f2(gxv[3].x), g1 = h2f2(gxv[3].y);
        a_c += (rg < 2) ? ((rg == 0) ? g0.x : g0.y) : ((rg == 2) ? g1.x : g1.y);
      }
      // i*tanh(c~) = (eC-1)/((1+eA)(eC+1))
      float eA = __expf(-fminf(fmaxf(a_i, -40.f), 40.f));
      float eC = __expf(2.f * fminf(fmaxf(a_c, -15.f), 15.f));
      float ict = (eC - 1.f) * __builtin_amdgcn_rcpf((1.f + eA) * (eC + 1.f));
      float eF = __expf(-fminf(fmaxf(a_f, -40.f), 40.f));
      float fg = __builtin_amdgcn_rcpf(1.f + eF);
      float cv = fg * cst[rg] + ict;
      cst[rg] = cv;
      // o*tanh(cv) = (eV-1)/((1+eO)(eV+1))
      float eO = __expf(-fminf(fmaxf(a_o, -40.f), 40.f));
      float eV = __expf(2.f * fminf(fmaxf(cv, -15.f), 15.f));
      float hv = (eV - 1.f) * __builtin_amdgcn_rcpf((1.f + eO) * (eV + 1.f));
      us[rg] = __half_as_ushort(__float2half_rn(hv));
      if (lastT) {
        int rrow = bg * 16 + kq * 4 + rg;
        dout[256 + (size_t)rrow * 256 + j] = hv;
        c_plain[(size_t)rrow * 256 + j] = cv;
      }
    }
#pragma unroll
    for (int q = 0; q < 4; ++q) gxv[q] = gnv[q];

    // ---- (vii) chunk end: persist own h-half for next chunk ----
    if (tt + 1 == tc) {
      if (!lastT) {
#pragma unroll
        for (int rg = 0; rg < 4; ++rg)
          h_state[(size_t)bg * 4096 + (kq * 4 + rg) * 256 + j] = __ushort_as_half(us[rg]);
      }
      break;
    }

    // ---- (viii) publish own h_{s+1}: hbuf (atomic ull) + own LDS region ----
    {
      unsigned long long pk = (unsigned long long)us[0] |
                              ((unsigned long long)us[1] << 16) |
                              ((unsigned long long)us[2] << 32) |
                              ((unsigned long long)us[3] << 48);
      unsigned long long* hbW =
          (unsigned long long*)hbuf + (((size_t)((s + 1) & 1)) * 16 + bg) * 1024;
      __hip_atomic_store(hbW + (size_t)j * 4 + kq, pk, __ATOMIC_RELAXED,
                         __HIP_MEMORY_SCOPE_AGENT);
#pragma unroll
      for (int rg = 0; rg < 4; ++rg) {
        int r = kq * 4 + rg;
        *(unsigned short*)(wb + r * 512 + ((j * 2) ^ ((r & 7) << 4))) = us[rg];
      }
    }

    // ---- (ix) fence + barrier + release flag ----
    __threadfence();
    __syncthreads();
    if (tid == 0)
      __hip_atomic_store(&flags[bid], (unsigned)(s + 1), __ATOMIC_RELEASE,
                         __HIP_MEMORY_SCOPE_AGENT);
  }

  // ---- save c state ----
#pragma unroll
  for (int rg = 0; rg < 4; ++rg) c_state[(size_t)bid * 2048 + tid * 4 + rg] = cst[rg];
}

// ---------------------------------------------------------------------------
// Phase 3: out[b] = sigmoid(hid[b,:].W2[:256] + cov[b,:].W2[256:] + b2)
// ---------------------------------------------------------------------------
__global__ void head_kernel(const float* __restrict__ hid, const float* __restrict__ cpl,
                            const float* __restrict__ W2, const float* __restrict__ b2,
                            float* __restrict__ out)
{
  int b = blockIdx.x, l = threadIdx.x;  // 64 threads
  float4 hv = ((const float4*)(hid + (size_t)b * 256))[l];
  float4 wv = ((const float4*)W2)[l];
  float s = hv.x * wv.x + hv.y * wv.y + hv.z * wv.z + hv.w * wv.w;
  float4 cv = ((const float4*)(cpl + (size_t)b * 256))[l];
  float4 wc = ((const float4*)(W2 + 256))[l];
  s += cv.x * wc.x + cv.y * wc.y + cv.z * wc.z + cv.w * wc.w;
#pragma unroll
  for (int off = 32; off > 0; off >>= 1) s += __shfl_down(s, off, 64);
  if (l == 0) out[b] = 1.f / (1.f + __expf(-(s + b2[0])));
}

// ---------------------------------------------------------------------------
extern "C" void kernel_launch(void* const* d_in, const int* in_sizes, int n_in,
                              void* d_out, int out_size, void* d_ws, size_t ws_size,
                              hipStream_t stream)
{
  const float* x  = (const float*)d_in[0];
  const float* Wi = (const float*)d_in[1];
  const float* bi = (const float*)d_in[2];
  const float* Wf = (const float*)d_in[3];
  const float* bf = (const float*)d_in[4];
  const float* Wo = (const float*)d_in[5];
  const float* bo = (const float*)d_in[6];
  const float* Wc = (const float*)d_in[7];
  const float* bc = (const float*)d_in[8];
  const float* W2 = (const float*)d_in[9];
  const float* b2 = (const float*)d_in[10];
  float* out = (float*)d_out;

  // ws: [gx TC*512K][c_plain 256K][c_state 256K][h_state 128K][hbuf 256K][w16x 256K][flags]
  char* ws = (char*)d_ws;
  const size_t state_bytes = (size_t)1280 * 1024;
  size_t avail = ws_size > state_bytes ? ws_size - state_bytes : 0;
  size_t tcap = avail / 524288;
  int TC = (int)(tcap > 1024 ? 1024 : (tcap & ~(size_t)7));
  if (TC < 8) TC = 8;  // requires ws_size >= ~5.5 MB
  __half* gxb = (__half*)ws;
  float* c_plain = (float*)(ws + (size_t)TC * 524288);
  float* c_state = c_plain + 65536;
  __half* h_state = (__half*)(c_state + 65536);
  __half* hbuf = h_state + 65536;
  __half* w16x = hbuf + 131072;
  unsigned* flags = (unsigned*)(w16x + 131072);

  w16_kernel<<<1024, 128, 0, stream>>>(Wi, Wf, Wo, Wc, w16x, flags);
  for (int t0 = 0; t0 < 1024; t0 += TC) {
    int tcn = (1024 - t0 < TC) ? (1024 - t0) : TC;
    gx_kernel<<<dim3(tcn / 8, 16, 2), 256, 0, stream>>>(w16x, bi, bf, bo, bc, x, gxb, t0);
    rec_kernel<<<32, 512, 0, stream>>>(Wi, Wf, Wo, Wc, gxb, out, c_plain, c_state,
                                       h_state, hbuf, flags, t0, tcn);
  }
  head_kernel<<<256, 64, 0, stream>>>(out + 256, c_plain, W2, b2, out);
}

// Round 8
// 3484.739 us; speedup vs baseline: 4.5527x; 4.5527x over previous
//
#include <hip/hip_runtime.h>
#include <hip/hip_fp16.h>

// LSTM: B=256, T=1024, D=128, H=256.
// w16_kernel: W x-part -> f16 table (once).
// gx_kernel : Gx = x@Wx^T + bias, f16, emitted PRE-SWAPPED into consumer-lane slots:
//             u32 gx[t][bg8 32][tile 16][gate 4][lane 64], lane holds 2 rows' f16.
// rec_kernel: 32 WGs (8 batch rows each) x 512 thr, 2 waves/SIMD. Wh: 46 frags/wave
//             in regs + 18 in LDS (144 KB). h dbuf 16 KB, 1 barrier/step, NO cross-WG
//             sync (batch rows independent). Rows 8-15 of the M=16 tile stay zero;
//             post-MFMA row redistribution via ds_bpermute (lane l pulls lane l&31)
//             so all 64 lanes do 2 activation elems per gate-pair (4 positions/lane).
// head_kernel: out[b] = sigmoid([hid, cov] @ W2^T + b2).

typedef _Float16 half8 __attribute__((ext_vector_type(8)));
typedef float f32x4 __attribute__((ext_vector_type(4)));

#define MFMA16(a, b, c) __builtin_amdgcn_mfma_f32_16x16x32_f16((a), (b), (c), 0, 0, 0)

__device__ __forceinline__ float2 h2f2(unsigned int u) {
  __half2 h;
  __builtin_memcpy(&h, &u, 4);
  return __half22float2(h);
}

// one LSTM element: returns h, updates c in place (R4-verified math)
__device__ __forceinline__ float lstm_elem(float a_i, float a_f, float a_o, float a_c,
                                           float& c) {
  float eA = __expf(-fminf(fmaxf(a_i, -40.f), 40.f));
  float eC = __expf(2.f * fminf(fmaxf(a_c, -15.f), 15.f));
  float ict = (eC - 1.f) * __builtin_amdgcn_rcpf((1.f + eA) * (eC + 1.f));
  float eF = __expf(-fminf(fmaxf(a_f, -40.f), 40.f));
  float fg = __builtin_amdgcn_rcpf(1.f + eF);
  float cv = fg * c + ict;
  c = cv;
  float eO = __expf(-fminf(fmaxf(a_o, -40.f), 40.f));
  float eV = __expf(2.f * fminf(fmaxf(cv, -15.f), 15.f));
  return (eV - 1.f) * __builtin_amdgcn_rcpf((1.f + eO) * (eV + 1.f));
}

// ---------------------------------------------------------------------------
// W x-part -> f16, rows g = q*256 + r, cols 0..127.
// ---------------------------------------------------------------------------
__global__ void w16_kernel(const float* __restrict__ Wi, const float* __restrict__ Wf,
                           const float* __restrict__ Wo, const float* __restrict__ Wc,
                           __half* __restrict__ w16x)
{
  int g = blockIdx.x, c = threadIdx.x;  // 1024 blocks x 128 threads
  int q = g >> 8;
  const float* Wq = (q == 0) ? Wi : (q == 1) ? Wf : (q == 2) ? Wo : Wc;
  w16x[g * 128 + c] = __float2half_rn(Wq[(size_t)(g & 255) * 384 + c]);
}

// ---------------------------------------------------------------------------
// Phase 1: x-part GEMM, no LDS. grid=(TC/8, 16 bg16, 2), 256 thr (4 waves).
// Producer lane (kqp=l>>4, col=l&15) holds rows16 kqp*4+rg; emits 2 u32:
//   bg8 = bg16*2 + (kqp>>1); lclo = (kqp&1)*16 + col;
//   gp[lclo] = pack(rg0, rg1);  gp[32+lclo] = pack(rg2, rg3);
//   gp = gx + (((tl*32 + bg8)*16 + t16)*4 + q)*64   (u32 units)
// ---------------------------------------------------------------------------
__global__ __launch_bounds__(256) void gx_kernel(
    const __half* __restrict__ w16x,
    const float* __restrict__ bi, const float* __restrict__ bf,
    const float* __restrict__ bo, const float* __restrict__ bc,
    const float* __restrict__ x, unsigned* __restrict__ gx, int t0)
{
  const int tid = threadIdx.x;
  const int l = tid & 63, wv = tid >> 6;
  const int kq = l >> 4, col = l & 15;
  const int tch = blockIdx.x, bg = blockIdx.y, gh = blockIdx.z;
  const size_t brow = (size_t)(bg * 16 + col);
  const int bg8 = bg * 2 + (kq >> 1);
  const int lclo = (kq & 1) * 16 + col;

#pragma unroll
  for (int mh = 0; mh < 2; ++mh) {
    half8 afr[4][4];
#pragma unroll
    for (int mm = 0; mm < 4; ++mm) {
      int tt = t0 + tch * 8 + mh * 4 + mm;
      const float* xp = x + (brow * 1024 + tt) * 128 + kq * 8;
#pragma unroll
      for (int k = 0; k < 4; ++k) {
        float4 a = *(const float4*)(xp + k * 32);
        float4 b = *(const float4*)(xp + k * 32 + 4);
        afr[mm][k] = {(_Float16)a.x, (_Float16)a.y, (_Float16)a.z, (_Float16)a.w,
                      (_Float16)b.x, (_Float16)b.y, (_Float16)b.z, (_Float16)b.w};
      }
    }
#pragma unroll
    for (int n = 0; n < 8; ++n) {
      int gbase = gh * 512 + wv * 128 + n * 16;
      int gcol = gbase + col;
      int q = gcol >> 8;
      const float* Bq = (q == 0) ? bi : (q == 1) ? bf : (q == 2) ? bo : bc;
      float bv = Bq[gcol & 255];
      half8 wf[4];
#pragma unroll
      for (int k = 0; k < 4; ++k)
        wf[k] = *(const half8*)(w16x + (size_t)(gbase + col) * 128 + k * 32 + kq * 8);
      int qg = gbase >> 8;
      int t16 = (gbase >> 4) & 15;
#pragma unroll
      for (int mm = 0; mm < 4; ++mm) {
        f32x4 acc = {bv, bv, bv, bv};
#pragma unroll
        for (int k = 0; k < 4; ++k) acc = MFMA16(afr[mm][k], wf[k], acc);
        int tl = tch * 8 + mh * 4 + mm;
        unsigned lo = (unsigned)__half_as_ushort(__float2half_rn(acc[0])) |
                      ((unsigned)__half_as_ushort(__float2half_rn(acc[1])) << 16);
        unsigned hi = (unsigned)__half_as_ushort(__float2half_rn(acc[2])) |
                      ((unsigned)__half_as_ushort(__float2half_rn(acc[3])) << 16);
        unsigned* gp = gx + ((((size_t)tl * 32 + bg8) * 16 + t16) * 4 + qg) * 64;
        gp[lclo] = lo;
        gp[32 + lclo] = hi;
      }
    }
  }
}

// ---------------------------------------------------------------------------
// Phase 2: recurrence. 32 WGs x 512 thr; WG bg8 owns batch rows bg8*8..+8.
// Wh frag linear index i = (ctl*4+q)*8+k; i<46 in regs, else per-wave LDS.
// ---------------------------------------------------------------------------
#define NFV 46

#define WFRAG(ctl, q, k)                                                      \
  ((((ctl) * 4 + (q)) * 8 + (k)) < NFV                                        \
       ? wfr[(((ctl) * 4 + (q)) * 8 + (k))]                                   \
       : *(const half8*)(WL + ((((ctl) * 4 + (q)) * 8 + (k)) - NFV) * 1024 + lofs))

__global__ __launch_bounds__(512) __attribute__((amdgpu_waves_per_eu(2, 2)))
void rec_kernel(
    const float* __restrict__ Wi, const float* __restrict__ Wf,
    const float* __restrict__ Wo, const float* __restrict__ Wc,
    const unsigned* __restrict__ gx, float* __restrict__ dout,
    float* __restrict__ c_plain, float* __restrict__ c_state,
    __half* __restrict__ h_state, int t0, int tc)
{
  __shared__ char lds[163840];  // 8 waves * 18 KB W frags (144K) + 16 KB h dbuf
  const int tid = threadIdx.x;
  const int l = tid & 63, w = tid >> 6;
  const int kq = l >> 4, col = l & 15;
  const int lofs = l * 16;
  const int bg8 = blockIdx.x;
  char* WL = lds + w * 18432;
  char* HF = lds + 147456;

  // ---- load Wh fragments (h-part cols [128,384)), j = (w*2+ctl)*16+col ----
  half8 wfr[NFV];
#pragma unroll
  for (int ctl = 0; ctl < 2; ++ctl) {
#pragma unroll
    for (int q = 0; q < 4; ++q) {
      const float* Wq = (q == 0) ? Wi : (q == 1) ? Wf : (q == 2) ? Wo : Wc;
      int j = (w * 2 + ctl) * 16 + col;
      const float* src = Wq + (size_t)j * 384 + 128 + kq * 8;
#pragma unroll
      for (int k = 0; k < 8; ++k) {
        float4 a = *(const float4*)(src + k * 32);
        float4 b = *(const float4*)(src + k * 32 + 4);
        half8 h = {(_Float16)a.x, (_Float16)a.y, (_Float16)a.z, (_Float16)a.w,
                   (_Float16)b.x, (_Float16)b.y, (_Float16)b.z, (_Float16)b.w};
        int i = (ctl * 4 + q) * 8 + k;
        if (i < NFV)
          wfr[i] = h;
        else
          *(half8*)(WL + (i - NFV) * 1024 + lofs) = h;
      }
    }
  }

  // ---- h-buffer init: zero rows 8..15 of both bufs (never written again) ----
  {
    uint4 z = {0, 0, 0, 0};
    *(uint4*)(HF + (tid >> 8) * 8192 + 4096 + (tid & 255) * 16) = z;
  }
  float cst[4];
  if (t0 == 0) {
#pragma unroll
    for (int i = 0; i < 4; ++i) cst[i] = 0.f;
    uint2 z2 = {0, 0};
    *(uint2*)(HF + tid * 8) = z2;  // zero rows 0..7 of buf0 (4 KB)
  } else {
#pragma unroll
    for (int i = 0; i < 4; ++i) cst[i] = c_state[(size_t)bg8 * 2048 + tid * 4 + i];
    int r8 = tid >> 6, c4 = tid & 63;
    uint2 v = *(const uint2*)(h_state + (size_t)bg8 * 2048 + r8 * 256 + c4 * 4);
    *(uint2*)(HF + ((t0 & 1) << 13) + r8 * 512 + ((c4 * 8) ^ ((r8 & 7) << 4))) = v;
  }

  // gx: 8 u32/step: offset ctl*1024 + q*256, step stride 524288 B (local tt).
  const char* gxw = (const char*)gx + ((size_t)bg8 * 16 + w * 2) * 1024 + l * 4;
  unsigned gxv[8];
#pragma unroll
  for (int c = 0; c < 8; ++c)
    gxv[c] = *(const unsigned*)(gxw + (c >> 2) * 1024 + (c & 3) * 256);

  const int rswz = (l & 7) << 4;
  const int rbase = (l & 15) * 512;
  const int hi5 = (l >> 5);
  const int baddr = (l & 31) * 4;  // ds_bpermute src: lane l pulls lane l&31

  for (int tt = 0; tt < tc; ++tt) {
    const int s = t0 + tt;
    const char* rb = HF + ((s & 1) << 13);
    char* wb = HF + (((s & 1) ^ 1) << 13);
    __syncthreads();  // prev-step writes (and init) visible
    const bool lastT = (s == 1023);
    const bool endC = (tt + 1 == tc);
    const char* gxn = gxw + (size_t)((tt + 1 < tc) ? tt + 1 : tt) * 524288;

#pragma unroll
    for (int ctl = 0; ctl < 2; ++ctl) {
      f32x4 acc[4] = {{0.f, 0.f, 0.f, 0.f}, {0.f, 0.f, 0.f, 0.f},
                      {0.f, 0.f, 0.f, 0.f}, {0.f, 0.f, 0.f, 0.f}};
#pragma unroll
      for (int kh = 0; kh < 2; ++kh) {
        half8 afr[4];
#pragma unroll
        for (int k2 = 0; k2 < 4; ++k2)
          afr[k2] = *(const half8*)(rb + rbase + (((kh * 4 + k2) * 64 + kq * 16) ^ rswz));
#pragma unroll
        for (int k2 = 0; k2 < 4; ++k2) {
          acc[0] = MFMA16(afr[k2], WFRAG(ctl, 0, kh * 4 + k2), acc[0]);
          acc[1] = MFMA16(afr[k2], WFRAG(ctl, 1, kh * 4 + k2), acc[1]);
          acc[2] = MFMA16(afr[k2], WFRAG(ctl, 2, kh * 4 + k2), acc[2]);
          acc[3] = MFMA16(afr[k2], WFRAG(ctl, 3, kh * 4 + k2), acc[3]);
        }
      }
      // ---- redistribute rows via ds_bpermute: lane l pulls src lane l&31.
      // Lane l wants rows rowb..rowb+1, rowb=(kq&1)*4+hi5*2: these live in
      // acc[q][hi5*2+e] at src lane (kq&1)*16+col = l&31. Unambiguous semantics.
      float P0[4], P1[4];
#pragma unroll
      for (int q = 0; q < 4; ++q) {
        int r0 = __builtin_amdgcn_ds_bpermute(baddr, __float_as_int(acc[q][0]));
        int r1 = __builtin_amdgcn_ds_bpermute(baddr, __float_as_int(acc[q][1]));
        int r2 = __builtin_amdgcn_ds_bpermute(baddr, __float_as_int(acc[q][2]));
        int r3 = __builtin_amdgcn_ds_bpermute(baddr, __float_as_int(acc[q][3]));
        P0[q] = __int_as_float(hi5 ? r2 : r0);
        P1[q] = __int_as_float(hi5 ? r3 : r1);
      }
      // ---- add gx (pre-swapped layout) ----
#pragma unroll
      for (int q = 0; q < 4; ++q) {
        float2 g = h2f2(gxv[ctl * 4 + q]);
        P0[q] += g.x;
        P1[q] += g.y;
      }
      // ---- activations: 2 positions/lane/ctl ----
      const int j2 = (w * 2 + ctl) * 16 + col;
      const int rowb = (kq & 1) * 4 + hi5 * 2;
      {  // e = 0
        float hv = lstm_elem(P0[0], P0[1], P0[2], P0[3], cst[ctl * 2 + 0]);
        int row = rowb;
        *(_Float16*)(wb + row * 512 + ((j2 * 2) ^ ((row & 7) << 4))) = (_Float16)hv;
        if (lastT) {
          int rrow = bg8 * 8 + row;
          dout[256 + (size_t)rrow * 256 + j2] = hv;
          c_plain[(size_t)rrow * 256 + j2] = cst[ctl * 2 + 0];
        } else if (endC) {
          h_state[(size_t)bg8 * 2048 + row * 256 + j2] = __float2half_rn(hv);
        }
      }
      {  // e = 1
        float hv = lstm_elem(P1[0], P1[1], P1[2], P1[3], cst[ctl * 2 + 1]);
        int row = rowb + 1;
        *(_Float16*)(wb + row * 512 + ((j2 * 2) ^ ((row & 7) << 4))) = (_Float16)hv;
        if (lastT) {
          int rrow = bg8 * 8 + row;
          dout[256 + (size_t)rrow * 256 + j2] = hv;
          c_plain[(size_t)rrow * 256 + j2] = cst[ctl * 2 + 1];
        } else if (endC) {
          h_state[(size_t)bg8 * 2048 + row * 256 + j2] = __float2half_rn(hv);
        }
      }
      // ---- refill this ctl-group's gx for next step (hides under next phase) ----
#pragma unroll
      for (int q = 0; q < 4; ++q)
        gxv[ctl * 4 + q] = *(const unsigned*)(gxn + ctl * 1024 + q * 256);
    }
  }

  // ---- save c state ----
#pragma unroll
  for (int i = 0; i < 4; ++i) c_state[(size_t)bg8 * 2048 + tid * 4 + i] = cst[i];
}

// ---------------------------------------------------------------------------
// Phase 3: out[b] = sigmoid(hid[b,:].W2[:256] + cov[b,:].W2[256:] + b2)
// ---------------------------------------------------------------------------
__global__ void head_kernel(const float* __restrict__ hid, const float* __restrict__ cpl,
                            const float* __restrict__ W2, const float* __restrict__ b2,
                            float* __restrict__ out)
{
  int b = blockIdx.x, l = threadIdx.x;  // 64 threads
  float4 hv = ((const float4*)(hid + (size_t)b * 256))[l];
  float4 wv = ((const float4*)W2)[l];
  float s = hv.x * wv.x + hv.y * wv.y + hv.z * wv.z + hv.w * wv.w;
  float4 cv = ((const float4*)(cpl + (size_t)b * 256))[l];
  float4 wc = ((const float4*)(W2 + 256))[l];
  s += cv.x * wc.x + cv.y * wc.y + cv.z * wc.z + cv.w * wc.w;
#pragma unroll
  for (int off = 32; off > 0; off >>= 1) s += __shfl_down(s, off, 64);
  if (l == 0) out[b] = 1.f / (1.f + __expf(-(s + b2[0])));
}

// ---------------------------------------------------------------------------
extern "C" void kernel_launch(void* const* d_in, const int* in_sizes, int n_in,
                              void* d_out, int out_size, void* d_ws, size_t ws_size,
                              hipStream_t stream)
{
  const float* x  = (const float*)d_in[0];
  const float* Wi = (const float*)d_in[1];
  const float* bi = (const float*)d_in[2];
  const float* Wf = (const float*)d_in[3];
  const float* bf = (const float*)d_in[4];
  const float* Wo = (const float*)d_in[5];
  const float* bo = (const float*)d_in[6];
  const float* Wc = (const float*)d_in[7];
  const float* bc = (const float*)d_in[8];
  const float* W2 = (const float*)d_in[9];
  const float* b2 = (const float*)d_in[10];
  float* out = (float*)d_out;

  // ws layout: [gx: TC*512KB][c_plain 256KB][c_state 256KB][h_state 128KB][w16x 256KB]
  char* ws = (char*)d_ws;
  const size_t state_bytes = (size_t)896 * 1024;
  size_t avail = ws_size > state_bytes ? ws_size - state_bytes : 0;
  size_t tcap = avail / 524288;
  int TC = (int)(tcap > 1024 ? 1024 : (tcap & ~(size_t)7));
  if (TC < 8) TC = 8;  // requires ws_size >= ~5.2 MB
  unsigned* gxb = (unsigned*)ws;
  float* c_plain = (float*)(ws + (size_t)TC * 524288);
  float* c_state = c_plain + 65536;
  __half* h_state = (__half*)(c_state + 65536);
  __half* w16x = (__half*)(h_state + 65536);

  w16_kernel<<<1024, 128, 0, stream>>>(Wi, Wf, Wo, Wc, w16x);
  for (int t0 = 0; t0 < 1024; t0 += TC) {
    int tcn = (1024 - t0 < TC) ? (1024 - t0) : TC;
    gx_kernel<<<dim3(tcn / 8, 16, 2), 256, 0, stream>>>(w16x, bi, bf, bo, bc, x, gxb, t0);
    rec_kernel<<<32, 512, 0, stream>>>(Wi, Wf, Wo, Wc, gxb, out, c_plain, c_state,
                                       h_state, t0, tcn);
  }
  head_kernel<<<256, 64, 0, stream>>>(out + 256, c_plain, W2, b2, out);
}